// Round 5
// baseline (6751.913 us; speedup 1.0000x reference)
//
#include <hip/hip_runtime.h>
#include <stdint.h>
#include <stdio.h>

// ---------------------------------------------------------------------------
// DilatedSparseRnnStack, round 5: round-4 XCD-local clusters + SPLIT barriers.
//  - ONE full cluster barrier per step (ring backpressure) instead of 4.
//  - Intra-step: per-layer producer flags flagO[l] (16 monotonic adds by the
//    g<16 out-producers). Consumers compute all old-segment GEMM partials
//    (prevH/dH/x, ~70% of MFMA) BEFORE waiting, so only a 16-MFMA tail +
//    cell sits behind each flag.
//  - L0 fold: dil=1 => dH == prevH, so Wd is folded into Wh at LDS-load
//    (K 320->192) and L0's alpha/C-ring is skipped (weightedC == prevC).
// 8 clusters (XCD-resident by construction) x 32 WGs x 8 SS-cols.
// ---------------------------------------------------------------------------

typedef __attribute__((ext_vector_type(8))) short short8;
typedef __attribute__((ext_vector_type(4))) float f32x4;

#define DEVINL static __device__ __forceinline__

constexpr int TT = 256, BBATCH = 1024, INW = 64, HSW = 128, OSW = 128, NO = 8;
constexpr int ROWS = 128;                 // batch rows per cluster

constexpr int DILa[4]  = {1, 3, 6, 12};
constexpr int PERa[4]  = {2, 4, 7, 13};   // h ring period = dil+1
constexpr int LDWa[4]  = {200, 392, 456, 392};   // padded LDS strides (ushorts)
constexpr int WOFFa[4] = {0, 6400, 18944, 33536};// ushort offsets (W0 folded K=192)

constexpr int GSTRIDE = 36;
constexpr int GATES_B = 46080 * 2;                 // 92,160 (end of weights)
constexpr int BIAS_B  = GATES_B + 128 * GSTRIDE * 4;   // 110,592
constexpr int WOUT_B  = BIAS_B + 128 * 4;              // 111,104
constexpr int WSTR    = 129;
constexpr int BOUT_B  = WOUT_B + 8 * WSTR * 4;         // 115,232
constexpr int LDS_BYTES = BOUT_B + 32;                 // 115,264

// workspace layout (bytes)
//   per-cluster control block c*1024: +0 stepbar, +128+l*128 flagO[l]
//   rank counters at 8192 + xcd*128
constexpr size_t WSBASE    = 16384;
constexpr size_t BH_OFF[4] = {0, 65536, 196608, 425984}; // h rings (P_l x 32768)
constexpr size_t OUTB_OFF  = 851968;                     // 4 x 128x128 bf16
constexpr size_t CB_OFF    = 983040;                     // C rings (L1..L3)
constexpr size_t CB_L[4]   = {0, 0, 393216, 1179648};    // within C region
constexpr size_t CLSZ      = 983040 + 2752512;           // 3,735,552
constexpr size_t WS_NEED   = WSBASE + 8 * CLSZ;          // 29,900,800

template <int N> struct IC { static constexpr int value = N; };

DEVINL unsigned short f2bf(float f) {        // RNE fp32 -> bf16
  union { float f; uint32_t u; } v; v.f = f;
  return (unsigned short)((v.u + 0x7FFFu + ((v.u >> 16) & 1u)) >> 16);
}
DEVINL float bf2f(unsigned short h) {
  union { uint32_t u; float f; } v; v.u = ((uint32_t)h) << 16;
  return v.f;
}
DEVINL float sigm(float x)  { return 1.0f / (1.0f + __expf(-x)); }
DEVINL float tanh_(float x) { return 1.0f - 2.0f / (__expf(2.0f * x) + 1.0f); }

DEVINL short8 zero_s8() { short8 v; for (int i = 0; i < 8; i++) v[i] = 0; return v; }
DEVINL f32x4  zero_f4() { f32x4  v; for (int i = 0; i < 4; i++) v[i] = 0.f; return v; }

DEVINL f32x4 mfma16(short8 a, short8 b, f32x4 c) {
  return __builtin_amdgcn_mfma_f32_16x16x32_bf16(a, b, c, 0, 0, 0);
}

DEVINL short8 ld8f(const float* p) {         // 8 fp32 -> bf16x8 fragment
  const f32x4 u0 = *(const f32x4*)p;
  const f32x4 u1 = *(const f32x4*)(p + 4);
  short8 r;
  r[0] = (short)f2bf(u0[0]); r[1] = (short)f2bf(u0[1]);
  r[2] = (short)f2bf(u0[2]); r[3] = (short)f2bf(u0[3]);
  r[4] = (short)f2bf(u1[0]); r[5] = (short)f2bf(u1[1]);
  r[6] = (short)f2bf(u1[2]); r[7] = (short)f2bf(u1[3]);
  return r;
}

__global__ void __launch_bounds__(256, 1)
rnn_stack_kernel(const float* __restrict__ x,
                 const float* __restrict__ W0, const float* __restrict__ b0,
                 const float* __restrict__ W1, const float* __restrict__ b1,
                 const float* __restrict__ W2, const float* __restrict__ b2,
                 const float* __restrict__ W3, const float* __restrict__ b3,
                 const float* __restrict__ Wout, const float* __restrict__ bout,
                 float* __restrict__ yout, char* __restrict__ ws)
{
  extern __shared__ char smem[];
  unsigned short* wlds = (unsigned short*)smem;
  float* gates = (float*)(smem + GATES_B);
  float* biasl = (float*)(smem + BIAS_B);
  float* woutl = (float*)(smem + WOUT_B);
  float* boutl = (float*)(smem + BOUT_B);

  const int tid = threadIdx.x;

  // ---- runtime cluster formation: c = physical XCD, g = rank on that XCD ----
  __shared__ unsigned s_cg;
  if (tid == 0) {
    unsigned xcc;
    asm volatile("s_getreg_b32 %0, hwreg(HW_REG_XCC_ID)" : "=s"(xcc));
    xcc &= 7u;
    unsigned rank = __hip_atomic_fetch_add(
        (unsigned*)(ws + 8192 + (size_t)xcc * 128), 1u,
        __ATOMIC_RELAXED, __HIP_MEMORY_SCOPE_AGENT);
    s_cg = (xcc << 8) | (rank & 31u);
  }
  __syncthreads();
  const int c = s_cg >> 8;         // cluster == XCD
  const int g = s_cg & 255;        // column-group 0..31 (SS cols g*8..g*8+7)

  unsigned* stepbar = (unsigned*)(ws + (size_t)c * 1024);
  unsigned* fl[4];
#pragma unroll
  for (int l = 0; l < 4; l++) fl[l] = (unsigned*)(ws + (size_t)c * 1024 + 128 + l * 128);

  char* cb = ws + WSBASE + (size_t)c * CLSZ;
  unsigned short* bufH[4];
  unsigned short* outb[4];
#pragma unroll
  for (int l = 0; l < 4; l++) {
    bufH[l] = (unsigned short*)(cb + BH_OFF[l]);
    outb[l] = (unsigned short*)(cb + OUTB_OFF + (size_t)l * ROWS * OSW * 2);
  }
  float* bufC[4];
#pragma unroll
  for (int l = 1; l < 4; l++)
    bufC[l] = (float*)(cb + CB_OFF + CB_L[l] + (size_t)g * ((size_t)DILa[l] * 4096));

  // ---- startup: weight/bias slices -> LDS (bf16); W0 gets dH folded ----
  {
    const float* Wsrc[4] = {W0, W1, W2, W3};
    const float* bsrc[4] = {b0, b1, b2, b3};
    const int Ksrc[4] = {320, 384, 448, 384};
    const int Kdst[4] = {192, 384, 448, 384};
    for (int l = 0; l < 4; l++) {
      const int LDW = LDWa[l];
      for (int n = 0; n < 32; n++) {
        const int grow = (n >> 3) * 256 + g * 8 + (n & 7);   // gate*SS + jglob
        const float* src = Wsrc[l] + (size_t)grow * Ksrc[l];
        unsigned short* dst = wlds + WOFFa[l] + n * LDW;
        if (l == 0) {
          for (int k = tid; k < 192; k += 256) {
            const float v = (k < 64) ? src[k] : (src[k] + src[k + 128]);
            dst[k] = f2bf(v);
          }
        } else {
          for (int k = tid; k < Kdst[l]; k += 256) dst[k] = f2bf(src[k]);
        }
      }
      if (tid < 32) biasl[l * 32 + tid] = bsrc[l][(tid >> 3) * 256 + g * 8 + (tid & 7)];
    }
    for (int i = tid; i < 8 * 128; i += 256) woutl[(i >> 7) * WSTR + (i & 127)] = Wout[i];
    if (tid < 8) boutl[tid] = bout[tid];
  }
  __syncthreads();

  f32x4 pc[4];
#pragma unroll
  for (int l = 0; l < 4; l++) pc[l] = zero_f4();

  const int wv = tid >> 6, lane = tid & 63, lm = lane & 15, quad = lane >> 4;
  const int m0 = wv * 32;          // wave's first batch row (2 M-tiles)

  // acquire-side wait: poll monotonic counter, then invalidate L1 (XCD-local)
  auto wait_ge = [&](unsigned* f, unsigned target) {
    if (tid == 0) {
      while (__hip_atomic_load(f, __ATOMIC_RELAXED, __HIP_MEMORY_SCOPE_AGENT) < target) {}
    }
    __syncthreads();
    asm volatile("buffer_inv sc0" ::: "memory");
  };

  auto mac4 = [&](f32x4* acc, short8 a0, short8 a1,
                  const unsigned short* wl, int LDW, int ktw) {
    const short8 bf0 = *(const short8*)(wl + (size_t)lm * LDW + ktw * 32 + quad * 8);
    const short8 bf1 = *(const short8*)(wl + (size_t)(16 + lm) * LDW + ktw * 32 + quad * 8);
    acc[0] = mfma16(a0, bf0, acc[0]);
    acc[1] = mfma16(a0, bf1, acc[1]);
    acc[2] = mfma16(a1, bf0, acc[2]);
    acc[3] = mfma16(a1, bf1, acc[3]);
  };
  // 4 consecutive ktiles from a bf16 row-major [128 x 128] buffer (or zeros)
  auto seg4 = [&](f32x4* acc, const unsigned short* wl, int LDW, int ktw0,
                  const unsigned short* src) {
#pragma unroll
    for (int i = 0; i < 4; i++) {
      short8 a0, a1;
      if (src) {
        const unsigned short* p = src + (size_t)(m0 + lm) * HSW + i * 32 + quad * 8;
        a0 = *(const short8*)p;
        a1 = *(const short8*)(p + 16 * HSW);
      } else { a0 = zero_s8(); a1 = zero_s8(); }
      mac4(acc, a0, a1, wl, LDW, ktw0 + i);
    }
  };

  // x fragments, prefetched one step ahead
  short8 xa00, xa01, xa10, xa11;
  {
    const float* xp = x + ((size_t)0 * BBATCH + (size_t)c * ROWS + m0 + lm) * INW + quad * 8;
    xa00 = ld8f(xp);       xa01 = ld8f(xp + 32);
    xa10 = ld8f(xp + 16 * INW); xa11 = ld8f(xp + 16 * INW + 32);
  }

  for (int t = 0; t < TT; t++) {
    // ---- step barrier: all WGs finished step t-1 (h rings / outb stable) ----
    wait_ge(stepbar, 32u * (unsigned)t);

    const unsigned ft = 16u * (unsigned)(t + 1);

    // cell + publish for layer L given its 4 gate accumulators
    auto cell_pub = [&](auto Lc, const f32x4* a) {
      constexpr int L = decltype(Lc)::value;
      constexpr int DL = DILa[L];
      constexpr int P  = PERa[L];
#pragma unroll
      for (int r = 0; r < 4; r++) {
        gates[(m0 + quad * 4 + r) * GSTRIDE + lm]           = a[0][r];
        gates[(m0 + quad * 4 + r) * GSTRIDE + 16 + lm]      = a[1][r];
        gates[(m0 + 16 + quad * 4 + r) * GSTRIDE + lm]      = a[2][r];
        gates[(m0 + 16 + quad * 4 + r) * GSTRIDE + 16 + lm] = a[3][r];
      }
      __syncthreads();
      {
        const int row = tid & 127, j0 = (tid >> 7) * 4;
        const f32x4 G0 = *(const f32x4*)&gates[row * GSTRIDE + 0 + j0];
        const f32x4 G1 = *(const f32x4*)&gates[row * GSTRIDE + 8 + j0];
        const f32x4 G2 = *(const f32x4*)&gates[row * GSTRIDE + 16 + j0];
        const f32x4 G3 = *(const f32x4*)&gates[row * GSTRIDE + 24 + j0];
        float* cs = nullptr;
        f32x4 dC = zero_f4();
        if constexpr (L > 0) {
          cs = bufC[L] + ((size_t)(t % DL) * ROWS + row) * 8 + j0;
          if (t >= DL) dC = *(const f32x4*)cs;
        }
        const f32x4 pcv = pc[L];
        f32x4 nC, wh;
#pragma unroll
        for (int q = 0; q < 4; q++) {
          const float fg = sigm(G0[q] + biasl[L * 32 + 0  + j0 + q] + 1.0f);
          const float cd = tanh_(G1[q] + biasl[L * 32 + 8  + j0 + q]);
          const float og = sigm(G3[q] + biasl[L * 32 + 24 + j0 + q]);
          float wc;
          if constexpr (L == 0) {
            wc = pcv[q];                    // alpha*pC+(1-alpha)*pC == pC
          } else {
            const float al = sigm(G2[q] + biasl[L * 32 + 16 + j0 + q]);
            wc = (t >= DL) ? (al * pcv[q] + (1.0f - al) * dC[q]) : pcv[q];
          }
          const float nc = (t >= 1) ? (fg * wc + (1.0f - fg) * cd) : cd;
          nC[q] = nc;
          wh[q] = og * nc;
        }
        if constexpr (L > 0) *(f32x4*)cs = nC;
        pc[L] = nC;
        ushort4 wb;
        wb.x = f2bf(wh[0]); wb.y = f2bf(wh[1]); wb.z = f2bf(wh[2]); wb.w = f2bf(wh[3]);
        const int jg = g * 8 + j0;
        if (g < 16) {
          *(ushort4*)(outb[L] + (size_t)row * OSW + jg) = wb;
        } else {
          *(ushort4*)(bufH[L] + ((size_t)(t % P) * ROWS + row) * HSW + (jg - 128)) = wb;
        }
      }
      __syncthreads();                           // all publishes drained to L2
      if (tid == 0 && g < 16)
        __hip_atomic_fetch_add(fl[L], 1u, __ATOMIC_RELAXED, __HIP_MEMORY_SCOPE_AGENT);
    };

    // ---- L0 head (K folded to 192: x kt0-1, prevH kt2-5) ----
    {
      const unsigned short* phb =
          (t >= 1) ? bufH[0] + (size_t)((t - 1) & 1) * ROWS * HSW : nullptr;
      f32x4 a0c[4] = {zero_f4(), zero_f4(), zero_f4(), zero_f4()};
      mac4(a0c, xa00, xa10, wlds + WOFFa[0], LDWa[0], 0);
      mac4(a0c, xa01, xa11, wlds + WOFFa[0], LDWa[0], 1);
      seg4(a0c, wlds + WOFFa[0], LDWa[0], 2, phb);
      cell_pub(IC<0>{}, a0c);
    }

    // ---- old-segment partials for L1..L3 (depend only on steps < t) ----
    f32x4 aL1[4] = {zero_f4(), zero_f4(), zero_f4(), zero_f4()};
    f32x4 aL2[4] = {zero_f4(), zero_f4(), zero_f4(), zero_f4()};
    f32x4 aL3[4] = {zero_f4(), zero_f4(), zero_f4(), zero_f4()};
    {
      const unsigned short* phb1 =
          (t >= 1) ? bufH[1] + (size_t)((t - 1) % 4) * ROWS * HSW : nullptr;
      const unsigned short* dhb1 =
          (t >= 3) ? bufH[1] + (size_t)((t - 3) % 4) * ROWS * HSW : phb1;
      seg4(aL1, wlds + WOFFa[1], LDWa[1], 4, phb1);
      seg4(aL1, wlds + WOFFa[1], LDWa[1], 8, dhb1);

      const unsigned short* phb2 =
          (t >= 1) ? bufH[2] + (size_t)((t - 1) % 7) * ROWS * HSW : nullptr;
      const unsigned short* dhb2 =
          (t >= 6) ? bufH[2] + (size_t)((t - 6) % 7) * ROWS * HSW : phb2;
      mac4(aL2, xa00, xa10, wlds + WOFFa[2], LDWa[2], 4);
      mac4(aL2, xa01, xa11, wlds + WOFFa[2], LDWa[2], 5);
      seg4(aL2, wlds + WOFFa[2], LDWa[2], 6, phb2);
      seg4(aL2, wlds + WOFFa[2], LDWa[2], 10, dhb2);

      const unsigned short* phb3 =
          (t >= 1) ? bufH[3] + (size_t)((t - 1) % 13) * ROWS * HSW : nullptr;
      const unsigned short* dhb3 =
          (t >= 12) ? bufH[3] + (size_t)((t - 12) % 13) * ROWS * HSW : phb3;
      seg4(aL3, wlds + WOFFa[3], LDWa[3], 4, phb3);
      seg4(aL3, wlds + WOFFa[3], LDWa[3], 8, dhb3);
    }

    // ---- L1 tail: wait out0, 4 ktiles, cell ----
    wait_ge(fl[0], ft);
    seg4(aL1, wlds + WOFFa[1], LDWa[1], 0, outb[0]);
    cell_pub(IC<1>{}, aL1);

    // ---- L2 tail ----
    wait_ge(fl[1], ft);
    seg4(aL2, wlds + WOFFa[2], LDWa[2], 0, outb[1]);
    cell_pub(IC<2>{}, aL2);

    // ---- L3 tail ----
    wait_ge(fl[2], ft);
    seg4(aL3, wlds + WOFFa[3], LDWa[3], 0, outb[2]);
    cell_pub(IC<3>{}, aL3);

    // ---- epilogue: y = out3 @ Wout^T + bout ----
    wait_ge(fl[3], ft);
    {
      const int o = (tid >> 3) & 7;
      const int s = tid & 7;
      const int r = g * 4 + (tid >> 6);
      const unsigned short* orow = outb[3] + (size_t)r * OSW;
      float part = 0.f;
#pragma unroll
      for (int i = 0; i < 16; i++) {
        const int k = s * 16 + i;
        part += bf2f(orow[k]) * woutl[o * WSTR + k];
      }
      part += __shfl_down(part, 4);
      part += __shfl_down(part, 2);
      part += __shfl_down(part, 1);
      if (s == 0)
        yout[((size_t)t * BBATCH + (size_t)c * ROWS + r) * NO + o] = part + boutl[o];
    }

    // ---- prefetch x for t+1, arrive at step barrier ----
    {
      const int tn = (t + 1 < TT) ? t + 1 : t;
      const float* xp = x + ((size_t)tn * BBATCH + (size_t)c * ROWS + m0 + lm) * INW + quad * 8;
      xa00 = ld8f(xp);            xa01 = ld8f(xp + 32);
      xa10 = ld8f(xp + 16 * INW); xa11 = ld8f(xp + 16 * INW + 32);
    }
    __syncthreads();
    if (tid == 0)
      __hip_atomic_fetch_add(stepbar, 1u, __ATOMIC_RELAXED, __HIP_MEMORY_SCOPE_AGENT);
  }
}

extern "C" void kernel_launch(void* const* d_in, const int* in_sizes, int n_in,
                              void* d_out, int out_size, void* d_ws, size_t ws_size,
                              hipStream_t stream) {
  const float* x    = (const float*)d_in[0];
  const float* W0   = (const float*)d_in[1];
  const float* b0   = (const float*)d_in[2];
  const float* W1   = (const float*)d_in[3];
  const float* b1   = (const float*)d_in[4];
  const float* W2   = (const float*)d_in[5];
  const float* b2   = (const float*)d_in[6];
  const float* W3   = (const float*)d_in[7];
  const float* b3   = (const float*)d_in[8];
  const float* Wout = (const float*)d_in[9];
  const float* bout = (const float*)d_in[10];
  float* out = (float*)d_out;
  char* ws = (char*)d_ws;

  if (ws_size < WS_NEED) {
    fprintf(stderr, "kernel_launch: ws_size %zu < needed %zu\n", ws_size, (size_t)WS_NEED);
    return;
  }

  // zero control region (step counters, flags, rank counters)
  hipMemsetAsync(d_ws, 0, WSBASE, stream);

  hipError_t e = hipFuncSetAttribute((const void*)rnn_stack_kernel,
                                     hipFuncAttributeMaxDynamicSharedMemorySize,
                                     LDS_BYTES);
  if (e != hipSuccess) fprintf(stderr, "hipFuncSetAttribute: %d\n", (int)e);

  rnn_stack_kernel<<<dim3(256), dim3(256), LDS_BYTES, stream>>>(
      x, W0, b0, W1, b1, W2, b2, W3, b3, Wout, bout, out, ws);
  e = hipGetLastError();
  if (e != hipSuccess) fprintf(stderr, "launch error: %d\n", (int)e);
}